// Round 1
// baseline (213.601 us; speedup 1.0000x reference)
//
#include <hip/hip_runtime.h>

// HashLoss: contrastive (logsumexp over ln@ln^T/0.2) + 0.5*MSE(H@H^T/128, Tn@Tn^T)
//         + 0.01*mean||logits|-1|
// B=4096, HASH=128, TD=768. Strategy: pack bf16 [ln|hash|tn] -> P[4096][1024],
// fused 64x64-tile MFMA kernel with K=1024 chunked through LDS.

#define BN 4096
#define TILE 64
#define LDS_PITCH 136  // 128 + 8 bf16 pad -> conflict-free ds_read_b128

typedef unsigned short u16x8 __attribute__((ext_vector_type(8)));
typedef __bf16 bf16x8 __attribute__((ext_vector_type(8)));
typedef float f32x4 __attribute__((ext_vector_type(4)));

__device__ __forceinline__ unsigned short f2bf(float f) {
  union { float f; unsigned int u; } v; v.f = f;
  unsigned int u = v.u;
  unsigned int r = (u + 0x7FFFu + ((u >> 16) & 1u)) >> 16;  // RNE
  return (unsigned short)r;
}

// ---- prep: normalize logits rows -> P[:,0:128]; hash -> P[:,128:256]; quant partials
__global__ __launch_bounds__(128) void prep_logits(const float* __restrict__ logits,
                                                   const float* __restrict__ hash,
                                                   unsigned short* __restrict__ P,
                                                   float* __restrict__ qpart) {
  const int r = blockIdx.x, t = threadIdx.x;
  const int wave = t >> 6, lane = t & 63;
  float x = logits[(size_t)r * 128 + t];
  float ss = x * x;
#pragma unroll
  for (int off = 1; off < 64; off <<= 1) ss += __shfl_xor(ss, off, 64);
  __shared__ float s2[2], q2[2];
  if (lane == 0) s2[wave] = ss;
  __syncthreads();
  float rn = 1.0f / fmaxf(sqrtf(s2[0] + s2[1]), 1e-12f);
  P[(size_t)r * 1024 + t] = f2bf(x * rn);
  P[(size_t)r * 1024 + 128 + t] = f2bf(hash[(size_t)r * 128 + t]);
  float qv = fabsf(fabsf(x) - 1.0f);
#pragma unroll
  for (int off = 1; off < 64; off <<= 1) qv += __shfl_xor(qv, off, 64);
  if (lane == 0) q2[wave] = qv;
  __syncthreads();
  if (t == 0) qpart[r] = q2[0] + q2[1];
}

// ---- prep: normalize teacher rows -> P[:,256:1024]
__global__ __launch_bounds__(256) void prep_teacher(const float* __restrict__ T,
                                                    unsigned short* __restrict__ P) {
  const int r = blockIdx.x, t = threadIdx.x;
  const int wave = t >> 6, lane = t & 63;
  float x0 = T[(size_t)r * 768 + t];
  float x1 = T[(size_t)r * 768 + 256 + t];
  float x2 = T[(size_t)r * 768 + 512 + t];
  float ss = x0 * x0 + x1 * x1 + x2 * x2;
#pragma unroll
  for (int off = 1; off < 64; off <<= 1) ss += __shfl_xor(ss, off, 64);
  __shared__ float s4[4];
  if (lane == 0) s4[wave] = ss;
  __syncthreads();
  float rn = 1.0f / fmaxf(sqrtf(s4[0] + s4[1] + s4[2] + s4[3]), 1e-12f);
  P[(size_t)r * 1024 + 256 + t] = f2bf(x0 * rn);
  P[(size_t)r * 1024 + 512 + t] = f2bf(x1 * rn);
  P[(size_t)r * 1024 + 768 + t] = f2bf(x2 * rn);
}

// ---- per-row positive counts. Mask dtype discriminator: byte 4097 is element
// (1,1) (diagonal, always true -> 1) under u8 layout, but a high byte of
// element 1024 (always 0) under i32/f32 layout.
__global__ __launch_bounds__(256) void cnt_kernel(const void* __restrict__ mask,
                                                  float* __restrict__ cnt) {
  const int r = blockIdx.x;
  const bool is_byte = ((const unsigned char*)mask)[4097] != 0;
  float c = 0.f;
  if (is_byte) {
    const unsigned char* m8 = (const unsigned char*)mask + (size_t)r * 4096;
    for (int j = threadIdx.x; j < 4096; j += 256) c += (m8[j] != 0) ? 1.f : 0.f;
  } else {
    const unsigned int* m32 = (const unsigned int*)mask + (size_t)r * 4096;
    for (int j = threadIdx.x; j < 4096; j += 256) c += (m32[j] != 0) ? 1.f : 0.f;
  }
#pragma unroll
  for (int off = 1; off < 64; off <<= 1) c += __shfl_xor(c, off, 64);
  __shared__ float s[4];
  if ((threadIdx.x & 63) == 0) s[threadIdx.x >> 6] = c;
  __syncthreads();
  if (threadIdx.x == 0) cnt[r] = s[0] + s[1] + s[2] + s[3];
}

// Stage a 64x128 chunk of P (rows base+0..63, cols KC*128..) for A and B sides,
// then 4 MFMA k-steps into the given 4 accumulators (16 rows x 64 cols per wave).
#define CHUNK(KC, A0, A1, A2, A3)                                              \
  {                                                                            \
    __syncthreads();                                                           \
    _Pragma("unroll") for (int it = 0; it < 4; ++it) {                         \
      int unit = (int)threadIdx.x + it * 256;                                  \
      int row = unit >> 4, cg = (unit & 15) << 3;                              \
      *(u16x8*)&As[row][cg] =                                                  \
          *(const u16x8*)&P[(size_t)(ti + row) * 1024 + (KC) * 128 + cg];      \
      *(u16x8*)&Bs[row][cg] =                                                  \
          *(const u16x8*)&P[(size_t)(tj + row) * 1024 + (KC) * 128 + cg];      \
    }                                                                          \
    __syncthreads();                                                           \
    _Pragma("unroll") for (int ks = 0; ks < 4; ++ks) {                         \
      bf16x8 af = *(const bf16x8*)&As[wave * 16 + l15][ks * 32 + qd * 8];      \
      bf16x8 b0 = *(const bf16x8*)&Bs[0 + l15][ks * 32 + qd * 8];              \
      A0 = __builtin_amdgcn_mfma_f32_16x16x32_bf16(af, b0, A0, 0, 0, 0);       \
      bf16x8 b1 = *(const bf16x8*)&Bs[16 + l15][ks * 32 + qd * 8];             \
      A1 = __builtin_amdgcn_mfma_f32_16x16x32_bf16(af, b1, A1, 0, 0, 0);       \
      bf16x8 b2 = *(const bf16x8*)&Bs[32 + l15][ks * 32 + qd * 8];             \
      A2 = __builtin_amdgcn_mfma_f32_16x16x32_bf16(af, b2, A2, 0, 0, 0);       \
      bf16x8 b3 = *(const bf16x8*)&Bs[48 + l15][ks * 32 + qd * 8];             \
      A3 = __builtin_amdgcn_mfma_f32_16x16x32_bf16(af, b3, A3, 0, 0, 0);       \
    }                                                                          \
  }

// ---- fused main kernel: 64x64 output tile per block, 4 waves x (16 rows x 64 cols)
__global__ __launch_bounds__(256) void hash_main(const unsigned short* __restrict__ P,
                                                 const void* __restrict__ mask,
                                                 float* __restrict__ rowexp,
                                                 float* __restrict__ possum,
                                                 float* __restrict__ dpart) {
  const int ti = blockIdx.y * TILE, tj = blockIdx.x * TILE;
  const int t = threadIdx.x;
  const int wave = t >> 6, lane = t & 63;
  const int qd = lane >> 4, l15 = lane & 15;

  __shared__ unsigned short As[TILE][LDS_PITCH];
  __shared__ unsigned short Bs[TILE][LDS_PITCH];
  __shared__ float red[4];

  f32x4 s0 = {0.f, 0.f, 0.f, 0.f}, s1 = s0, s2 = s0, s3 = s0;  // ln gram
  f32x4 h0 = s0, h1 = s0, h2 = s0, h3 = s0;                    // hash gram
  f32x4 t0 = s0, t1 = s0, t2 = s0, t3 = s0;                    // teacher gram

  CHUNK(0, s0, s1, s2, s3);
  CHUNK(1, h0, h1, h2, h3);
#pragma unroll
  for (int kc = 2; kc < 8; ++kc) CHUNK(kc, t0, t1, t2, t3);

  const f32x4 Sv[4] = {s0, s1, s2, s3};
  const f32x4 Hv[4] = {h0, h1, h2, h3};
  const f32x4 Tv[4] = {t0, t1, t2, t3};

  const bool is_byte = ((const unsigned char*)mask)[4097] != 0;
  const unsigned char* m8 = (const unsigned char*)mask;
  const unsigned int* m32 = (const unsigned int*)mask;

  float dsum = 0.f;
#pragma unroll
  for (int r = 0; r < 4; ++r) {
    const int m = ti + wave * 16 + qd * 4 + r;  // D layout: row=(lane>>4)*4+r
    float se = 0.f, sp = 0.f;
#pragma unroll
    for (int nt = 0; nt < 4; ++nt) {
      const int n = tj + nt * 16 + l15;  // D layout: col=lane&15
      float sim = Sv[nt][r] * 5.0f;      // /TEMPERATURE
      if (m != n) se += __expf(sim);     // diag excluded from logsumexp
      unsigned int pm = is_byte ? (unsigned int)m8[(size_t)m * 4096 + n]
                                : m32[(size_t)m * 4096 + n];
      if (pm) sp += sim;                 // pos uses sim WITH diagonal
      float d = Hv[nt][r] * 0.0078125f - Tv[nt][r];  // /HASH_BITS
      dsum += d * d;
    }
#pragma unroll
    for (int off = 1; off < 16; off <<= 1) {
      se += __shfl_xor(se, off, 64);
      sp += __shfl_xor(sp, off, 64);
    }
    if (l15 == 0) {
      atomicAdd(&rowexp[m], se);
      atomicAdd(&possum[m], sp);
    }
  }
#pragma unroll
  for (int off = 1; off < 64; off <<= 1) dsum += __shfl_xor(dsum, off, 64);
  if (lane == 0) red[wave] = dsum;
  __syncthreads();
  if (t == 0) dpart[blockIdx.y * 64 + blockIdx.x] = red[0] + red[1] + red[2] + red[3];
}

// ---- final scalar assembly
__global__ __launch_bounds__(1024) void finalize(const float* __restrict__ rowexp,
                                                 const float* __restrict__ possum,
                                                 const float* __restrict__ cnt,
                                                 const float* __restrict__ qpart,
                                                 const float* __restrict__ dpart,
                                                 float* __restrict__ out) {
  const int t = threadIdx.x;
  const int wave = t >> 6, lane = t & 63;
  float c = 0.f, q = 0.f, d = 0.f;
  for (int m = t; m < 4096; m += 1024) {
    c += logf(rowexp[m]) - possum[m] / fmaxf(cnt[m], 1.0f);
    q += qpart[m];
    d += dpart[m];
  }
#pragma unroll
  for (int off = 1; off < 64; off <<= 1) {
    c += __shfl_xor(c, off, 64);
    q += __shfl_xor(q, off, 64);
    d += __shfl_xor(d, off, 64);
  }
  __shared__ float sc[16], sq[16], sd[16];
  if (lane == 0) { sc[wave] = c; sq[wave] = q; sd[wave] = d; }
  __syncthreads();
  if (t == 0) {
    float C = 0.f, Q = 0.f, D = 0.f;
    for (int i = 0; i < 16; ++i) { C += sc[i]; Q += sq[i]; D += sd[i]; }
    // cont: every row has its diagonal positive -> num_pos = B
    out[0] = C * (1.0f / 4096.0f) + 0.5f * (D * (1.0f / 16777216.0f)) +
             0.01f * (Q * (1.0f / 524288.0f));
  }
}

extern "C" void kernel_launch(void* const* d_in, const int* in_sizes, int n_in,
                              void* d_out, int out_size, void* d_ws, size_t ws_size,
                              hipStream_t stream) {
  const float* logits = (const float*)d_in[0];
  const float* hash = (const float*)d_in[1];
  const float* teacher = (const float*)d_in[2];
  const void* mask = d_in[3];
  float* out = (float*)d_out;

  char* ws = (char*)d_ws;
  float* rowexp = (float*)(ws + 0);            // 4096 f32, atomically accumulated
  float* possum = (float*)(ws + 16384);        // 4096 f32, atomically accumulated
  float* cntp = (float*)(ws + 32768);          // 4096 f32
  float* qpart = (float*)(ws + 49152);         // 4096 f32
  float* dpart = (float*)(ws + 65536);         // 4096 f32
  unsigned short* P = (unsigned short*)(ws + 98304);  // 4096x1024 bf16 = 8 MB

  hipMemsetAsync(d_ws, 0, 32768, stream);  // zero rowexp+possum only
  prep_logits<<<4096, 128, 0, stream>>>(logits, hash, P, qpart);
  prep_teacher<<<4096, 256, 0, stream>>>(teacher, P);
  cnt_kernel<<<4096, 256, 0, stream>>>(mask, cntp);
  hash_main<<<dim3(64, 64), 256, 0, stream>>>(P, mask, rowexp, possum, dpart);
  finalize<<<1, 1024, 0, stream>>>(rowexp, possum, cntp, qpart, dpart, out);
}

// Round 2
// 206.193 us; speedup vs baseline: 1.0359x; 1.0359x over previous
//
#include <hip/hip_runtime.h>

// HashLoss: contrastive (logsumexp over ln@ln^T/0.2) + 0.5*MSE(H@H^T/128, Tn@Tn^T)
//         + 0.01*mean||logits|-1|
// B=4096. Pack bf16 [ln|hash|tn] -> P[4096][1024]. Triangle-only (2080 of 4096
// 64x64 tiles; Grams symmetric, mask is not -> mirror epilogue reads pm[n][m]).
// Staging via global_load_lds(16B) into XOR-swizzled pitch-128 LDS.

typedef unsigned short u16x8 __attribute__((ext_vector_type(8)));
typedef __bf16 bf16x8 __attribute__((ext_vector_type(8)));
typedef float f32x4 __attribute__((ext_vector_type(4)));

__device__ __forceinline__ unsigned short f2bf(float f) {
  union { float f; unsigned int u; } v; v.f = f;
  unsigned int u = v.u;
  return (unsigned short)((u + 0x7FFFu + ((u >> 16) & 1u)) >> 16);  // RNE
}

// ---- fused prep: teacher norm -> P[:,256:1024]; logits norm -> P[:,0:128];
// hash -> P[:,128:256]; quant partial; zero the atomic accumulators.
__global__ __launch_bounds__(256) void prep(const float* __restrict__ logits,
                                            const float* __restrict__ hash,
                                            const float* __restrict__ teacher,
                                            unsigned short* __restrict__ P,
                                            float* __restrict__ qpart,
                                            float* __restrict__ rowexp,
                                            float* __restrict__ possum,
                                            float* __restrict__ cntw) {
  const int r = blockIdx.x, t = threadIdx.x;
  const int wave = t >> 6, lane = t & 63;
  __shared__ float s4[4], s2[2], q2[2];

  float x0 = teacher[(size_t)r * 768 + t];
  float x1 = teacher[(size_t)r * 768 + 256 + t];
  float x2 = teacher[(size_t)r * 768 + 512 + t];
  float ss = x0 * x0 + x1 * x1 + x2 * x2;
#pragma unroll
  for (int off = 1; off < 64; off <<= 1) ss += __shfl_xor(ss, off, 64);
  if (lane == 0) s4[wave] = ss;

  float xl = 0.f;
  if (t < 128) {
    xl = logits[(size_t)r * 128 + t];
    float ssl = xl * xl;
    float qv = fabsf(fabsf(xl) - 1.0f);
#pragma unroll
    for (int off = 1; off < 64; off <<= 1) {
      ssl += __shfl_xor(ssl, off, 64);
      qv += __shfl_xor(qv, off, 64);
    }
    if (lane == 0) { s2[wave] = ssl; q2[wave] = qv; }
  }
  __syncthreads();

  float rnt = 1.0f / fmaxf(sqrtf(s4[0] + s4[1] + s4[2] + s4[3]), 1e-12f);
  P[(size_t)r * 1024 + 256 + t] = f2bf(x0 * rnt);
  P[(size_t)r * 1024 + 512 + t] = f2bf(x1 * rnt);
  P[(size_t)r * 1024 + 768 + t] = f2bf(x2 * rnt);
  if (t < 128) {
    float rnl = 1.0f / fmaxf(sqrtf(s2[0] + s2[1]), 1e-12f);
    P[(size_t)r * 1024 + t] = f2bf(xl * rnl);
    P[(size_t)r * 1024 + 128 + t] = f2bf(hash[(size_t)r * 128 + t]);
  }
  if (t == 0) {
    qpart[r] = q2[0] + q2[1];
    rowexp[r] = 0.f; possum[r] = 0.f; cntw[r] = 0.f;
  }
}

// Stage chunk kc (64 rows x 128 cols) of A (rows ti+) and, if offdiag, B (tj+)
// via global_load_lds. LDS layout: row*128 + (g ^ (row&7))*8 holds col-group g.
#define STAGE(KC)                                                              \
  {                                                                            \
    _Pragma("unroll") for (int it = 0; it < 4; ++it) {                         \
      const int seg = it * 4 + wave;                                           \
      const int row = seg * 4 + (lane >> 4);                                   \
      const int g = (lane & 15) ^ (row & 7);                                   \
      const unsigned short* gpA =                                              \
          P + (size_t)(ti + row) * 1024 + (KC) * 128 + g * 8;                  \
      __builtin_amdgcn_global_load_lds(                                        \
          (const __attribute__((address_space(1))) void*)gpA,                  \
          (__attribute__((address_space(3))) void*)&S[seg * 512], 16, 0, 0);   \
      if (offdiag) {                                                           \
        const unsigned short* gpB =                                            \
            P + (size_t)(tj + row) * 1024 + (KC) * 128 + g * 8;                \
        __builtin_amdgcn_global_load_lds(                                      \
            (const __attribute__((address_space(1))) void*)gpB,                \
            (__attribute__((address_space(3))) void*)&S[8192 + seg * 512],     \
            16, 0, 0);                                                         \
      }                                                                        \
    }                                                                          \
  }

#define CHUNK_MFMA(A0, A1, A2, A3)                                             \
  {                                                                            \
    _Pragma("unroll") for (int ks = 0; ks < 4; ++ks) {                         \
      const int gg = (ks * 4 + qd) ^ swz;                                      \
      bf16x8 af = *(const bf16x8*)&S[(wave * 16 + l15) * 128 + gg * 8];        \
      bf16x8 b0 = *(const bf16x8*)&S[boff + l15 * 128 + gg * 8];               \
      A0 = __builtin_amdgcn_mfma_f32_16x16x32_bf16(af, b0, A0, 0, 0, 0);       \
      bf16x8 b1 = *(const bf16x8*)&S[boff + (16 + l15) * 128 + gg * 8];        \
      A1 = __builtin_amdgcn_mfma_f32_16x16x32_bf16(af, b1, A1, 0, 0, 0);       \
      bf16x8 b2 = *(const bf16x8*)&S[boff + (32 + l15) * 128 + gg * 8];        \
      A2 = __builtin_amdgcn_mfma_f32_16x16x32_bf16(af, b2, A2, 0, 0, 0);       \
      bf16x8 b3 = *(const bf16x8*)&S[boff + (48 + l15) * 128 + gg * 8];        \
      A3 = __builtin_amdgcn_mfma_f32_16x16x32_bf16(af, b3, A3, 0, 0, 0);       \
    }                                                                          \
  }

__global__ __launch_bounds__(256) void hash_main(const unsigned short* __restrict__ P,
                                                 const void* __restrict__ mask,
                                                 float* __restrict__ rowexp,
                                                 float* __restrict__ possum,
                                                 float* __restrict__ cntw,
                                                 float* __restrict__ dpart) {
  // ---- triangle decode: linear id -> (bi, bj), bi <= bj, bi-major
  const int l = (int)blockIdx.x;
  int bi = (int)((129.0f - sqrtf(16641.0f - 8.0f * (float)l)) * 0.5f);
  while (bi * (129 - bi) / 2 > l) --bi;
  while ((bi + 1) * (128 - bi) / 2 <= l) ++bi;
  const int bj = bi + (l - bi * (129 - bi) / 2);
  const int ti = bi * 64, tj = bj * 64;
  const bool offdiag = (bi != bj);

  const int t = threadIdx.x;
  const int wave = t >> 6, lane = t & 63;
  const int qd = lane >> 4, l15 = lane & 15;
  const int swz = l15 & 7;

  __shared__ __align__(16) unsigned short S[16384];  // A @0, B @8192 (shorts)
  __shared__ float red[4];
  const int boff = offdiag ? 8192 : 0;

  f32x4 s0 = {0.f, 0.f, 0.f, 0.f}, s1 = s0, s2 = s0, s3 = s0;  // ln gram
  f32x4 h0 = s0, h1 = s0, h2 = s0, h3 = s0;                    // hash gram
  f32x4 t0 = s0, t1 = s0, t2 = s0, t3 = s0;                    // teacher gram

  STAGE(0); __syncthreads(); CHUNK_MFMA(s0, s1, s2, s3);
  __syncthreads(); STAGE(1); __syncthreads(); CHUNK_MFMA(h0, h1, h2, h3);
#pragma unroll
  for (int kc = 2; kc < 8; ++kc) {
    __syncthreads(); STAGE(kc); __syncthreads(); CHUNK_MFMA(t0, t1, t2, t3);
  }

  const f32x4 Sv[4] = {s0, s1, s2, s3};
  const f32x4 Hv[4] = {h0, h1, h2, h3};
  const f32x4 Tv[4] = {t0, t1, t2, t3};

  // mask dtype: byte 4097 = element (1,1) diag (1) if u8; high byte (0) if i32.
  const bool is_byte = ((const unsigned char*)mask)[4097] != 0;
  const unsigned char* m8 = (const unsigned char*)mask;
  const unsigned int* m32 = (const unsigned int*)mask;

  float dsum = 0.f;
  float colexp[4] = {0.f, 0.f, 0.f, 0.f};
  float colpos[4] = {0.f, 0.f, 0.f, 0.f};
  float colcnt[4] = {0.f, 0.f, 0.f, 0.f};

#pragma unroll
  for (int r = 0; r < 4; ++r) {
    const int m = ti + wave * 16 + qd * 4 + r;  // C/D: row=(lane>>4)*4+reg
    float se = 0.f, sp = 0.f, sc = 0.f;
#pragma unroll
    for (int nt = 0; nt < 4; ++nt) {
      const int n = tj + nt * 16 + l15;         // C/D: col=lane&15
      const float sim = Sv[nt][r] * 5.0f;       // /TEMPERATURE
      const float e = __expf(sim);
      if (offdiag || m != n) se += e;           // logsumexp excludes diagonal
      const unsigned int pmd = is_byte ? (unsigned int)m8[(size_t)m * 4096 + n]
                                       : (unsigned int)(m32[(size_t)m * 4096 + n] != 0);
      if (pmd) { sp += sim; sc += 1.f; }        // pos sum uses sim WITH diagonal
      if (offdiag) {                            // mirror entry (n, m)
        colexp[nt] += e;
        const unsigned int pmm = is_byte ? (unsigned int)m8[(size_t)n * 4096 + m]
                                         : (unsigned int)(m32[(size_t)n * 4096 + m] != 0);
        if (pmm) { colpos[nt] += sim; colcnt[nt] += 1.f; }
      }
      const float d = Hv[nt][r] * 0.0078125f - Tv[nt][r];  // /HASH_BITS
      dsum += d * d;
    }
#pragma unroll
    for (int off = 1; off < 16; off <<= 1) {
      se += __shfl_xor(se, off, 64);
      sp += __shfl_xor(sp, off, 64);
      sc += __shfl_xor(sc, off, 64);
    }
    if (l15 == 0) {
      atomicAdd(&rowexp[m], se);
      atomicAdd(&possum[m], sp);
      atomicAdd(&cntw[m], sc);
    }
  }
  if (offdiag) {
#pragma unroll
    for (int nt = 0; nt < 4; ++nt) {
      float ce = colexp[nt], cp = colpos[nt], cc = colcnt[nt];
      ce += __shfl_xor(ce, 16, 64); ce += __shfl_xor(ce, 32, 64);
      cp += __shfl_xor(cp, 16, 64); cp += __shfl_xor(cp, 32, 64);
      cc += __shfl_xor(cc, 16, 64); cc += __shfl_xor(cc, 32, 64);
      if (qd == 0) {
        const int n = tj + nt * 16 + l15;
        atomicAdd(&rowexp[n], ce);
        atomicAdd(&possum[n], cp);
        atomicAdd(&cntw[n], cc);
      }
    }
  }
#pragma unroll
  for (int off = 1; off < 64; off <<= 1) dsum += __shfl_xor(dsum, off, 64);
  if (lane == 0) red[wave] = dsum;
  __syncthreads();
  if (t == 0)
    dpart[l] = (offdiag ? 2.0f : 1.0f) * (red[0] + red[1] + red[2] + red[3]);
}

__global__ __launch_bounds__(1024) void finalize(const float* __restrict__ rowexp,
                                                 const float* __restrict__ possum,
                                                 const float* __restrict__ cnt,
                                                 const float* __restrict__ qpart,
                                                 const float* __restrict__ dpart,
                                                 float* __restrict__ out) {
  const int t = threadIdx.x;
  const int wave = t >> 6, lane = t & 63;
  float c = 0.f, q = 0.f, d = 0.f;
  for (int m = t; m < 4096; m += 1024) {
    c += logf(rowexp[m]) - possum[m] / fmaxf(cnt[m], 1.0f);
    q += qpart[m];
  }
  for (int i = t; i < 2080; i += 1024) d += dpart[i];
#pragma unroll
  for (int off = 1; off < 64; off <<= 1) {
    c += __shfl_xor(c, off, 64);
    q += __shfl_xor(q, off, 64);
    d += __shfl_xor(d, off, 64);
  }
  __shared__ float sc[16], sq[16], sd[16];
  if (lane == 0) { sc[wave] = c; sq[wave] = q; sd[wave] = d; }
  __syncthreads();
  if (t == 0) {
    float C = 0.f, Q = 0.f, D = 0.f;
    for (int i = 0; i < 16; ++i) { C += sc[i]; Q += sq[i]; D += sd[i]; }
    // every row has its diagonal positive -> num_pos = B = 4096
    out[0] = C * (1.0f / 4096.0f) + 0.5f * (D * (1.0f / 16777216.0f)) +
             0.01f * (Q * (1.0f / 524288.0f));
  }
}

extern "C" void kernel_launch(void* const* d_in, const int* in_sizes, int n_in,
                              void* d_out, int out_size, void* d_ws, size_t ws_size,
                              hipStream_t stream) {
  const float* logits = (const float*)d_in[0];
  const float* hash = (const float*)d_in[1];
  const float* teacher = (const float*)d_in[2];
  const void* mask = d_in[3];
  float* out = (float*)d_out;

  char* ws = (char*)d_ws;
  float* rowexp = (float*)(ws + 0);
  float* possum = (float*)(ws + 16384);
  float* cntw = (float*)(ws + 32768);
  float* qpart = (float*)(ws + 49152);
  float* dpart = (float*)(ws + 65536);  // 2080 floats
  unsigned short* P = (unsigned short*)(ws + 98304);  // 4096x1024 bf16 = 8 MB

  prep<<<4096, 256, 0, stream>>>(logits, hash, teacher, P, qpart, rowexp, possum, cntw);
  hash_main<<<2080, 256, 0, stream>>>(P, mask, rowexp, possum, cntw, dpart);
  finalize<<<1, 1024, 0, stream>>>(rowexp, possum, cntw, qpart, dpart, out);
}

// Round 3
// 189.563 us; speedup vs baseline: 1.1268x; 1.0877x over previous
//
#include <hip/hip_runtime.h>

// HashLoss: contrastive (logsumexp over ln@ln^T/0.2) + 0.5*MSE(H@H^T/128, Tn@Tn^T)
//         + 0.01*mean||logits|-1|
// B=4096. Pack bf16 [ln | hash/sqrt(128) | tn] -> P[4096][1024]. Triangle-only
// (2080 64x64 tiles). Two accumulator sets: S (contrastive) and D = Hs - T via
// negate-then-continue MFMA. Mask tiles staged coalesced into LDS for epilogue.

typedef unsigned short u16x8 __attribute__((ext_vector_type(8)));
typedef __bf16 bf16x8 __attribute__((ext_vector_type(8)));
typedef float f32x4 __attribute__((ext_vector_type(4)));

__device__ __forceinline__ unsigned short f2bf(float f) {
  union { float f; unsigned int u; } v; v.f = f;
  unsigned int u = v.u;
  return (unsigned short)((u + 0x7FFFu + ((u >> 16) & 1u)) >> 16);  // RNE
}

// ---- fused prep: teacher norm -> P[:,256:1024]; logits norm -> P[:,0:128];
// hash/sqrt(128) -> P[:,128:256]; quant partial; zero atomic accumulators.
__global__ __launch_bounds__(256) void prep(const float* __restrict__ logits,
                                            const float* __restrict__ hash,
                                            const float* __restrict__ teacher,
                                            unsigned short* __restrict__ P,
                                            float* __restrict__ qpart,
                                            float* __restrict__ rowexp,
                                            float* __restrict__ possum,
                                            float* __restrict__ cntw) {
  const int r = blockIdx.x, t = threadIdx.x;
  const int wave = t >> 6, lane = t & 63;
  __shared__ float s4[4], s2[2], q2[2];

  float x0 = teacher[(size_t)r * 768 + t];
  float x1 = teacher[(size_t)r * 768 + 256 + t];
  float x2 = teacher[(size_t)r * 768 + 512 + t];
  float ss = x0 * x0 + x1 * x1 + x2 * x2;
#pragma unroll
  for (int off = 1; off < 64; off <<= 1) ss += __shfl_xor(ss, off, 64);
  if (lane == 0) s4[wave] = ss;

  float xl = 0.f;
  if (t < 128) {
    xl = logits[(size_t)r * 128 + t];
    float ssl = xl * xl;
    float qv = fabsf(fabsf(xl) - 1.0f);
#pragma unroll
    for (int off = 1; off < 64; off <<= 1) {
      ssl += __shfl_xor(ssl, off, 64);
      qv += __shfl_xor(qv, off, 64);
    }
    if (lane == 0) { s2[wave] = ssl; q2[wave] = qv; }
  }
  __syncthreads();

  float rnt = 1.0f / fmaxf(sqrtf(s4[0] + s4[1] + s4[2] + s4[3]), 1e-12f);
  P[(size_t)r * 1024 + 256 + t] = f2bf(x0 * rnt);
  P[(size_t)r * 1024 + 512 + t] = f2bf(x1 * rnt);
  P[(size_t)r * 1024 + 768 + t] = f2bf(x2 * rnt);
  if (t < 128) {
    float rnl = 1.0f / fmaxf(sqrtf(s2[0] + s2[1]), 1e-12f);
    P[(size_t)r * 1024 + t] = f2bf(xl * rnl);
    // hash/sqrt(128): (H/sqrt128)@(H/sqrt128)^T == H@H^T/128
    P[(size_t)r * 1024 + 128 + t] =
        f2bf(hash[(size_t)r * 128 + t] * 0.08838834764831845f);
  }
  if (t == 0) {
    qpart[r] = q2[0] + q2[1];
    rowexp[r] = 0.f; possum[r] = 0.f; cntw[r] = 0.f;
  }
}

// Stage chunk kc (64 rows x 128 cols) of A (rows ti+) and, if offdiag, B (tj+)
// via global_load_lds. LDS layout: row*128 + (g ^ (row&7))*8 holds col-group g.
#define STAGE(KC)                                                              \
  {                                                                            \
    _Pragma("unroll") for (int it = 0; it < 4; ++it) {                         \
      const int seg = it * 4 + wave;                                           \
      const int row = seg * 4 + (lane >> 4);                                   \
      const int g = (lane & 15) ^ (row & 7);                                   \
      const unsigned short* gpA =                                              \
          P + (size_t)(ti + row) * 1024 + (KC) * 128 + g * 8;                  \
      __builtin_amdgcn_global_load_lds(                                        \
          (const __attribute__((address_space(1))) void*)gpA,                  \
          (__attribute__((address_space(3))) void*)&S[seg * 512], 16, 0, 0);   \
      if (offdiag) {                                                           \
        const unsigned short* gpB =                                            \
            P + (size_t)(tj + row) * 1024 + (KC) * 128 + g * 8;                \
        __builtin_amdgcn_global_load_lds(                                      \
            (const __attribute__((address_space(1))) void*)gpB,                \
            (__attribute__((address_space(3))) void*)&S[8192 + seg * 512],     \
            16, 0, 0);                                                         \
      }                                                                        \
    }                                                                          \
  }

#define CHUNK_MFMA(A0, A1, A2, A3)                                             \
  {                                                                            \
    _Pragma("unroll") for (int ks = 0; ks < 4; ++ks) {                         \
      const int gg = (ks * 4 + qd) ^ swz;                                      \
      bf16x8 af = *(const bf16x8*)&S[(wave * 16 + l15) * 128 + gg * 8];        \
      bf16x8 b0 = *(const bf16x8*)&S[boff + l15 * 128 + gg * 8];               \
      A0 = __builtin_amdgcn_mfma_f32_16x16x32_bf16(af, b0, A0, 0, 0, 0);       \
      bf16x8 b1 = *(const bf16x8*)&S[boff + (16 + l15) * 128 + gg * 8];        \
      A1 = __builtin_amdgcn_mfma_f32_16x16x32_bf16(af, b1, A1, 0, 0, 0);       \
      bf16x8 b2 = *(const bf16x8*)&S[boff + (32 + l15) * 128 + gg * 8];        \
      A2 = __builtin_amdgcn_mfma_f32_16x16x32_bf16(af, b2, A2, 0, 0, 0);       \
      bf16x8 b3 = *(const bf16x8*)&S[boff + (48 + l15) * 128 + gg * 8];        \
      A3 = __builtin_amdgcn_mfma_f32_16x16x32_bf16(af, b3, A3, 0, 0, 0);       \
    }                                                                          \
  }

__global__ __launch_bounds__(256) void hash_main(const unsigned short* __restrict__ P,
                                                 const void* __restrict__ mask,
                                                 float* __restrict__ rowexp,
                                                 float* __restrict__ possum,
                                                 float* __restrict__ cntw,
                                                 float* __restrict__ dpart) {
  // XCD swizzle: 2080 = 8*260; give each XCD a contiguous triangle run.
  const int b = (int)blockIdx.x;
  const int l = (b & 7) * 260 + (b >> 3);
  // triangle decode: l -> (bi, bj), bi <= bj
  int bi = (int)((129.0f - sqrtf(16641.0f - 8.0f * (float)l)) * 0.5f);
  while (bi * (129 - bi) / 2 > l) --bi;
  while ((bi + 1) * (128 - bi) / 2 <= l) ++bi;
  const int bj = bi + (l - bi * (129 - bi) / 2);
  const int ti = bi * 64, tj = bj * 64;
  const bool offdiag = (bi != bj);

  const int t = threadIdx.x;
  const int wave = t >> 6, lane = t & 63;
  const int qd = lane >> 4, l15 = lane & 15;
  const int swz = l15 & 7;

  __shared__ __align__(16) unsigned short S[16384];  // A @0, B @8192 (shorts)
  __shared__ float red[4];
  const int boff = offdiag ? 8192 : 0;

  f32x4 s0 = {0.f, 0.f, 0.f, 0.f}, s1 = s0, s2 = s0, s3 = s0;  // ln gram
  f32x4 d0 = s0, d1 = s0, d2 = s0, d3 = s0;                    // Hs - T

  STAGE(0); __syncthreads(); CHUNK_MFMA(s0, s1, s2, s3);
#pragma unroll
  for (int kc = 2; kc < 8; ++kc) {
    __syncthreads(); STAGE(kc); __syncthreads(); CHUNK_MFMA(d0, d1, d2, d3);
  }
  d0 = -d0; d1 = -d1; d2 = -d2; d3 = -d3;  // acc = -T
  __syncthreads(); STAGE(1); __syncthreads();
  CHUNK_MFMA(d0, d1, d2, d3);              // acc = Hs - T

  const f32x4 Sv[4] = {s0, s1, s2, s3};
  const f32x4 Dv[4] = {d0, d1, d2, d3};

  // ---- mask tiles -> LDS (coalesced), reusing first 8KB of S ----
  __syncthreads();
  unsigned char* MD = (unsigned char*)S;         // [mrow][ncol]
  unsigned char* MM = (unsigned char*)S + 4096;  // [ncol][mrow] (mirror rows)
  const bool is_byte = ((const unsigned char*)mask)[4097] != 0;
  const unsigned char* m8 = (const unsigned char*)mask;
  const unsigned int* m32 = (const unsigned int*)mask;
  if (is_byte) {
    const int row = t >> 2, seg = t & 3;
    *(uint4*)&MD[row * 64 + seg * 16] =
        *(const uint4*)&m8[(size_t)(ti + row) * 4096 + tj + seg * 16];
    if (offdiag)
      *(uint4*)&MM[row * 64 + seg * 16] =
          *(const uint4*)&m8[(size_t)(tj + row) * 4096 + ti + seg * 16];
  } else {
#pragma unroll
    for (int p = 0; p < 4; ++p) {
      const int unit = t + p * 256;
      const int row = unit >> 4, seg = unit & 15;
      uint4 v = *(const uint4*)&m32[(size_t)(ti + row) * 4096 + tj + seg * 4];
      uchar4 pk;
      pk.x = v.x ? 1 : 0; pk.y = v.y ? 1 : 0; pk.z = v.z ? 1 : 0; pk.w = v.w ? 1 : 0;
      *(uchar4*)&MD[row * 64 + seg * 4] = pk;
      if (offdiag) {
        uint4 w = *(const uint4*)&m32[(size_t)(tj + row) * 4096 + ti + seg * 4];
        uchar4 pm;
        pm.x = w.x ? 1 : 0; pm.y = w.y ? 1 : 0; pm.z = w.z ? 1 : 0; pm.w = w.w ? 1 : 0;
        *(uchar4*)&MM[row * 64 + seg * 4] = pm;
      }
    }
  }
  __syncthreads();

  float dsum = 0.f;
  float colexp[4] = {0.f, 0.f, 0.f, 0.f};
#pragma unroll
  for (int r = 0; r < 4; ++r) {
    const int mrow = wave * 16 + qd * 4 + r;  // C/D: row=(lane>>4)*4+reg
    const int m = ti + mrow;
    float se = 0.f;
#pragma unroll
    for (int nt = 0; nt < 4; ++nt) {
      const int ncol = nt * 16 + l15;         // C/D: col=lane&15
      const int n = tj + ncol;
      const float sim = Sv[nt][r] * 5.0f;     // /TEMPERATURE
      const float e = __expf(sim);
      if (offdiag || m != n) se += e;         // logsumexp excludes diagonal
      if (offdiag) colexp[nt] += e;
      if (MD[mrow * 64 + ncol]) {             // sparse positives: direct atomics
        atomicAdd(&possum[m], sim);
        atomicAdd(&cntw[m], 1.0f);
      }
      if (offdiag && MM[ncol * 64 + mrow]) {  // mirror entry (n, m)
        atomicAdd(&possum[n], sim);
        atomicAdd(&cntw[n], 1.0f);
      }
      const float dv = Dv[nt][r];
      dsum += dv * dv;
    }
#pragma unroll
    for (int off = 1; off < 16; off <<= 1) se += __shfl_xor(se, off, 64);
    if (l15 == 0) atomicAdd(&rowexp[m], se);
  }
  if (offdiag) {
#pragma unroll
    for (int nt = 0; nt < 4; ++nt) {
      float ce = colexp[nt];
      ce += __shfl_xor(ce, 16, 64); ce += __shfl_xor(ce, 32, 64);
      if (qd == 0) atomicAdd(&rowexp[tj + nt * 16 + l15], ce);
    }
  }
#pragma unroll
  for (int off = 1; off < 64; off <<= 1) dsum += __shfl_xor(dsum, off, 64);
  if (lane == 0) red[wave] = dsum;
  __syncthreads();
  if (t == 0)
    dpart[l] = (offdiag ? 2.0f : 1.0f) * (red[0] + red[1] + red[2] + red[3]);
}

__global__ __launch_bounds__(1024) void finalize(const float* __restrict__ rowexp,
                                                 const float* __restrict__ possum,
                                                 const float* __restrict__ cnt,
                                                 const float* __restrict__ qpart,
                                                 const float* __restrict__ dpart,
                                                 float* __restrict__ out) {
  const int t = threadIdx.x;
  const int wave = t >> 6, lane = t & 63;
  float c = 0.f, q = 0.f, d = 0.f;
  for (int m = t; m < 4096; m += 1024) {
    c += logf(rowexp[m]) - possum[m] / fmaxf(cnt[m], 1.0f);
    q += qpart[m];
  }
  for (int i = t; i < 2080; i += 1024) d += dpart[i];
#pragma unroll
  for (int off = 1; off < 64; off <<= 1) {
    c += __shfl_xor(c, off, 64);
    q += __shfl_xor(q, off, 64);
    d += __shfl_xor(d, off, 64);
  }
  __shared__ float sc[16], sq[16], sd[16];
  if (lane == 0) { sc[wave] = c; sq[wave] = q; sd[wave] = d; }
  __syncthreads();
  if (t == 0) {
    float C = 0.f, Q = 0.f, D = 0.f;
    for (int i = 0; i < 16; ++i) { C += sc[i]; Q += sq[i]; D += sd[i]; }
    // every row has its diagonal positive -> num_pos = B = 4096
    out[0] = C * (1.0f / 4096.0f) + 0.5f * (D * (1.0f / 16777216.0f)) +
             0.01f * (Q * (1.0f / 524288.0f));
  }
}

extern "C" void kernel_launch(void* const* d_in, const int* in_sizes, int n_in,
                              void* d_out, int out_size, void* d_ws, size_t ws_size,
                              hipStream_t stream) {
  const float* logits = (const float*)d_in[0];
  const float* hash = (const float*)d_in[1];
  const float* teacher = (const float*)d_in[2];
  const void* mask = d_in[3];
  float* out = (float*)d_out;

  char* ws = (char*)d_ws;
  float* rowexp = (float*)(ws + 0);
  float* possum = (float*)(ws + 16384);
  float* cntw = (float*)(ws + 32768);
  float* qpart = (float*)(ws + 49152);
  float* dpart = (float*)(ws + 65536);  // 2080 floats
  unsigned short* P = (unsigned short*)(ws + 98304);  // 4096x1024 bf16 = 8 MB

  prep<<<4096, 256, 0, stream>>>(logits, hash, teacher, P, qpart, rowexp, possum, cntw);
  hash_main<<<2080, 256, 0, stream>>>(P, mask, rowexp, possum, cntw, dpart);
  finalize<<<1, 1024, 0, stream>>>(rowexp, possum, cntw, qpart, dpart, out);
}